// Round 10
// baseline (55.541 us; speedup 1.0000x reference)
//
#include <hip/hip_runtime.h>
#include <hip/hip_bf16.h>

#define IN_F   4096
#define OUT_F  11008
#define BATCH  32
#define GROUP  128
#define NTILE  16
#define GRID_N (OUT_F / NTILE)    // 688
#define OUTSZ  (BATCH * OUT_F)    // 352256
#define REPEAT 3                  // 2 dummy passes (->ws) + 1 real (->out): measurement round

typedef __attribute__((ext_vector_type(8))) short  bf16x8;
typedef __attribute__((ext_vector_type(4))) float  f32x4;
typedef __attribute__((ext_vector_type(4))) int    i32x4;

static __device__ __constant__ float NF4_LEVELS[16] = {
    -1.0f, -0.6961928009986877f, -0.5250730514526367f, -0.39491748809814453f,
    -0.28444138169288635f, -0.18477343022823334f, -0.09105003625154495f, 0.0f,
    0.07958029955625534f, 0.16093020141124725f, 0.24611230194568634f,
    0.33791524171829224f, 0.44070982933044434f, 0.5626170039176941f,
    0.7229568362236023f, 1.0f};

// ws layout: frag 256KB at 0 | dummy-out 2*OUTSZ floats at 1MB
#define WS_DUMP_OFF (1 << 20)

// ---------------------------------------------------------------------------
// Prelude (64 blocks): A-fragment streams in MFMA order only.
//   frag[st][kb][lane] (16B) = x[st*16+(lane&15)][kb*32+(lane>>4)*8 .. +8) bf16
// ---------------------------------------------------------------------------
__global__ void prelude_kernel(const float* __restrict__ x,
                               unsigned short* __restrict__ frag) {
    int T  = blockIdx.x * 256 + threadIdx.x;
    int st = T >> 13;
    int kb = (T >> 6) & 127;
    int l  = T & 63;
    int row = st * 16 + (l & 15);
    int k0  = kb * 32 + (l >> 4) * 8;
    const float* src = x + (size_t)row * IN_F + k0;
    unsigned w[4];
    #pragma unroll
    for (int e = 0; e < 4; ++e) {
        unsigned lo = __builtin_bit_cast(unsigned short, __float2bfloat16(src[2 * e]));
        unsigned hi = __builtin_bit_cast(unsigned short, __float2bfloat16(src[2 * e + 1]));
        w[e] = lo | (hi << 16);
    }
    i32x4 v = { (int)w[0], (int)w[1], (int)w[2], (int)w[3] };
    *reinterpret_cast<i32x4*>(frag + ((size_t)st * 8192 + kb * 64 + l) * 8) = v;
}

// ---------------------------------------------------------------------------
// Main: grid (688, REPEAT), 256 thr (4 waves), 3 blocks/CU.
// Block = 16 out-rows x FULL K=4096 as 8 units of 512k. No atomics, no
// partial buffer: direct store of (sum over waves) + bias.
// Waves split each unit's K 4-ways (wave w owns scale-group u*4+w).
//
// Pipeline (stage-ahead-2, vmcnt never drained in-loop):
//   iter u: issue loads(u+2) -> compute(u) from buf[u&1] -> write(u+1)
//           -> barrier.  Writes(u+1) target buf[!(u&1)], last read at u-1
//           (protected by the previous barrier); reads(u) protected by the
//           barrier after write(u) in iter u-1.
// Staging per unit: wave w stages rows w*4..+3; one row-chunk = 256 int32 =
//   one contiguous 1KB wave-load; compact 4 int32 -> 1 code-dword (j=lane).
//   Store at (row*64 + p(j)) ^ ((row&7)<<2), p(j)=(j&0x30)|((j&3)<<2)|((j>>2)&3)
//   -> reader ds_read_b128 at (col*64 + w*16 + g*4) ^ ((col&7)<<2) gives
//   k-steps t=0..3; writes 2-way banks, reads 2-way banks (both free).
// ---------------------------------------------------------------------------
__global__ __launch_bounds__(256, 3) void nf4_gemm_kernel(
        const int* __restrict__ packed,
        const float* __restrict__ scales,
        const float* __restrict__ bias,
        const unsigned short* __restrict__ frag,
        float* __restrict__ out,
        float* __restrict__ dump)
{
    __shared__ unsigned tabu[256];
    __shared__ float    slds[512];       // scales[16 rows][32 groups] transposed
    __shared__ unsigned buf[2][1024];    // 2 x 4KB code dwords; red alias (8KB)

    const int tid  = threadIdx.x;
    const int wave = tid >> 6;
    const int lane = tid & 63;
    const int col  = lane & 15;
    const int g    = lane >> 4;

    {
        unsigned lo = __builtin_bit_cast(unsigned short, __float2bfloat16(NF4_LEVELS[tid & 15]));
        unsigned hi = __builtin_bit_cast(unsigned short, __float2bfloat16(NF4_LEVELS[(tid >> 4) & 15]));
        tabu[tid] = lo | (hi << 16);
    }

    const int n0 = blockIdx.x * NTILE;

    // stage scales for this block's 16 rows: contiguous 2KB -> slds[gr][col]
    {
        int e = tid * 2;
        float2 sv = *reinterpret_cast<const float2*>(scales + (size_t)n0 * 32 + e);
        int c0 = e >> 5, g0 = e & 31;
        slds[g0 * 16 + c0]       = sv.x;
        slds[(g0 + 1) * 16 + c0] = sv.y;
    }

    const int dperm = (lane & 0x30) | ((lane & 3) << 2) | ((lane >> 2) & 3);

    #define PLOAD(u, sr)                                                       \
        _Pragma("unroll")                                                      \
        for (int ii = 0; ii < 4; ++ii) {                                       \
            sr[ii] = *reinterpret_cast<const i32x4*>(                          \
                packed + (size_t)(n0 + wave * 4 + ii) * (IN_F / 2)             \
                       + (u) * 256 + lane * 4);                                \
        }

    #define PWRITE(u, sr)                                                      \
        _Pragma("unroll")                                                      \
        for (int ii = 0; ii < 4; ++ii) {                                       \
            int row = wave * 4 + ii;                                           \
            unsigned v = ((unsigned)(sr[ii][0] & 255))                         \
                       | ((unsigned)(sr[ii][1] & 255) << 8)                    \
                       | ((unsigned)(sr[ii][2] & 255) << 16)                   \
                       | ((unsigned)(sr[ii][3] & 255) << 24);                  \
            buf[(u) & 1][(row * 64 + dperm) ^ ((row & 7) << 2)] = v;           \
        }

    // prologue: loads for units 0 and 1 in flight; write unit 0
    i32x4 sB[4];
    {
        i32x4 sA[4];
        PLOAD(0, sA)
        PLOAD(1, sB)
        PWRITE(0, sA)
    }
    __syncthreads();

    f32x4 acc0 = (f32x4){0.f,0.f,0.f,0.f};   // batch 0-15
    f32x4 acc1 = (f32x4){0.f,0.f,0.f,0.f};   // batch 16-31

    const unsigned short* f0 = frag;
    const unsigned short* f1 = frag + 65536;

    #pragma unroll
    for (int u = 0; u < 8; ++u) {
        i32x4 sC[4];
        if (u + 2 < 8) { PLOAD(u + 2, sC) }      // issue early; never drain

        // A fragments for this unit (8 x 1KB contiguous, L2-resident)
        bf16x8 A0[4], A1[4];
        #pragma unroll
        for (int t = 0; t < 4; ++t) {
            int kb = u * 16 + wave * 4 + t;
            A0[t] = *reinterpret_cast<const bf16x8*>(f0 + ((size_t)kb * 64 + lane) * 8);
            A1[t] = *reinterpret_cast<const bf16x8*>(f1 + ((size_t)kb * 64 + lane) * 8);
        }

        i32x4 cdv = *reinterpret_cast<const i32x4*>(
            &buf[u & 1][(col * 64 + wave * 16 + g * 4) ^ ((col & 7) << 2)]);
        float sc = slds[(u * 4 + wave) * 16 + col];

        f32x4 t0 = (f32x4){0.f,0.f,0.f,0.f};
        f32x4 t1 = (f32x4){0.f,0.f,0.f,0.f};
        #pragma unroll
        for (int t = 0; t < 4; ++t) {
            unsigned code = (unsigned)cdv[t];
            i32x4 bu;
            bu[0] = (int)tabu[code & 255u];
            bu[1] = (int)tabu[(code >> 8) & 255u];
            bu[2] = (int)tabu[(code >> 16) & 255u];
            bu[3] = (int)tabu[code >> 24];
            bf16x8 bf = __builtin_bit_cast(bf16x8, bu);
            t0 = __builtin_amdgcn_mfma_f32_16x16x32_bf16(A0[t], bf, t0, 0, 0, 0);
            t1 = __builtin_amdgcn_mfma_f32_16x16x32_bf16(A1[t], bf, t1, 0, 0, 0);
        }
        #pragma unroll
        for (int j = 0; j < 4; ++j) {
            acc0[j] = fmaf(sc, t0[j], acc0[j]);
            acc1[j] = fmaf(sc, t1[j], acc1[j]);
        }

        if (u + 1 < 8) { PWRITE(u + 1, sB) }     // into buf[!(u&1)], safe
        #pragma unroll
        for (int ii = 0; ii < 4; ++ii) sB[ii] = sC[ii];   // rotate (renamed)

        __syncthreads();
    }

    // ---- cross-wave K-reduce in aliased LDS, direct store + bias ----
    float* red = (float*)buf;
    #pragma unroll
    for (int j = 0; j < 4; ++j) {
        red[wave * 512 + j * 64 + lane]         = acc0[j];
        red[wave * 512 + (4 + j) * 64 + lane]   = acc1[j];
    }
    __syncthreads();

    float* dst = (blockIdx.y == REPEAT - 1) ? out : dump + (size_t)blockIdx.y * OUTSZ;
    #pragma unroll
    for (int p = 0; p < 2; ++p) {
        int idx = p * 256 + tid;             // [0,512): b = idx>>4, c = idx&15
        int b   = idx >> 4;
        int c   = idx & 15;
        int h   = b >> 4;
        int r4  = b & 15;
        int j   = r4 & 3;
        int lg  = r4 >> 2;
        int slot = (h * 4 + j) * 64 + lg * 16 + c;
        float s = red[slot] + red[512 + slot] + red[1024 + slot] + red[1536 + slot];
        dst[(size_t)b * OUT_F + n0 + c] = s + bias[n0 + c];
    }
}

// ---------------------------------------------------------------------------
extern "C" void kernel_launch(void* const* d_in, const int* in_sizes, int n_in,
                              void* d_out, int out_size, void* d_ws, size_t ws_size,
                              hipStream_t stream) {
    const float* x      = (const float*)d_in[0];
    const int*   packed = (const int*)d_in[1];
    const float* scales = (const float*)d_in[2];
    const float* bias   = (const float*)d_in[3];
    float* out = (float*)d_out;

    char* ws = (char*)d_ws;
    unsigned short* frag = (unsigned short*)ws;
    float* dump = (float*)(ws + WS_DUMP_OFF);

    prelude_kernel<<<64, 256, 0, stream>>>(x, frag);
    nf4_gemm_kernel<<<dim3(GRID_N, REPEAT), 256, 0, stream>>>(
        packed, scales, bias, frag, out, dump);
}

// Round 11
// 28.610 us; speedup vs baseline: 1.9413x; 1.9413x over previous
//
#include <hip/hip_runtime.h>
#include <hip/hip_bf16.h>

#define IN_F   4096
#define OUT_F  11008
#define BATCH  32
#define GROUP  128
#define NTILE  16
#define KSPLIT 4
#define GRID_N (OUT_F / NTILE)    // 688
#define OUTSZ  (BATCH * OUT_F)    // 352256

typedef __attribute__((ext_vector_type(8))) short  bf16x8;
typedef __attribute__((ext_vector_type(4))) float  f32x4;
typedef __attribute__((ext_vector_type(4))) int    i32x4;
typedef __attribute__((ext_vector_type(4))) float  float4v;

static __device__ __constant__ float NF4_LEVELS[16] = {
    -1.0f, -0.6961928009986877f, -0.5250730514526367f, -0.39491748809814453f,
    -0.28444138169288635f, -0.18477343022823334f, -0.09105003625154495f, 0.0f,
    0.07958029955625534f, 0.16093020141124725f, 0.24611230194568634f,
    0.33791524171829224f, 0.44070982933044434f, 0.5626170039176941f,
    0.7229568362236023f, 1.0f};

// ---------------------------------------------------------------------------
// Prelude (408 blocks):
//   bid <  64: A-fragment streams in MFMA order:
//     frag[st][kb][lane] (16B) = x[st*16+(lane&15)][kb*32+(lane>>4)*8..+8) bf16
//   bid >= 64: out[b][o] = bias[o]  (base for gemm atomics)
// ---------------------------------------------------------------------------
__global__ void prelude_kernel(const float* __restrict__ x,
                               const float* __restrict__ bias,
                               unsigned short* __restrict__ frag,
                               float* __restrict__ out) {
    const int bid = blockIdx.x, tid = threadIdx.x;
    if (bid < 64) {
        int T  = bid * 256 + tid;
        int st = T >> 13;
        int kb = (T >> 6) & 127;
        int l  = T & 63;
        int row = st * 16 + (l & 15);
        int k0  = kb * 32 + (l >> 4) * 8;
        const float* src = x + (size_t)row * IN_F + k0;
        unsigned w[4];
        #pragma unroll
        for (int e = 0; e < 4; ++e) {
            unsigned lo = __builtin_bit_cast(unsigned short, __float2bfloat16(src[2 * e]));
            unsigned hi = __builtin_bit_cast(unsigned short, __float2bfloat16(src[2 * e + 1]));
            w[e] = lo | (hi << 16);
        }
        i32x4 v = { (int)w[0], (int)w[1], (int)w[2], (int)w[3] };
        *reinterpret_cast<i32x4*>(frag + ((size_t)st * 8192 + kb * 64 + l) * 8) = v;
    } else {
        int t2 = (bid - 64) * 256 + tid;     // [0, 88064)
        int i  = t2 * 4;
        int o  = i % OUT_F;                  // OUT_F%4==0 -> aligned
        float4v b = *reinterpret_cast<const float4v*>(bias + o);
        *reinterpret_cast<float4v*>(out + i) = b;
    }
}

// ---------------------------------------------------------------------------
// Main: grid (688, 4) = 2752 blocks, 256 thr (4 waves), 8 blocks/CU target
// (32 waves/CU). Block = 16 out-rows x 1024 k as 2 units of 512 k.
// Waves split each unit's K 4-ways (wave w owns scale-group of its slice).
//
// Staging per unit: wave w stages rows w*4..+3; one row-chunk = 256 int32 =
//   one contiguous 1KB wave-load; compact 4 int32 -> 1 code-dword (j=lane).
//   Store at (row*64 + p(j)) ^ ((row&7)<<2), p(j)=(j&0x30)|((j&3)<<2)|((j>>2)&3)
//   -> reader ds_read_b128 at (col*64 + w*16 + g*4) ^ ((col&7)<<2) gives
//   k-steps t=0..3; writes 2-way banks, reads 2-way banks (both free).
// Epilogue: cross-wave LDS reduce, unsafeAtomicAdd into bias-init'd out.
// ---------------------------------------------------------------------------
__global__ __launch_bounds__(256, 8) void nf4_gemm_kernel(
        const int* __restrict__ packed,
        const float* __restrict__ scales,
        const unsigned short* __restrict__ frag,
        float* __restrict__ out)
{
    __shared__ unsigned tabu[256];
    __shared__ float    slds[512];       // scales[16 rows][32 groups] transposed
    __shared__ unsigned buf[2][1024];    // 2 x 4KB code dwords; red alias (8KB)

    const int tid  = threadIdx.x;
    const int wave = tid >> 6;
    const int lane = tid & 63;
    const int col  = lane & 15;
    const int g    = lane >> 4;

    {
        unsigned lo = __builtin_bit_cast(unsigned short, __float2bfloat16(NF4_LEVELS[tid & 15]));
        unsigned hi = __builtin_bit_cast(unsigned short, __float2bfloat16(NF4_LEVELS[(tid >> 4) & 15]));
        tabu[tid] = lo | (hi << 16);
    }

    const int n0 = blockIdx.x * NTILE;

    // stage all 32 groups' scales for this block's 16 rows (2KB contiguous)
    {
        int e = tid * 2;
        float2 sv = *reinterpret_cast<const float2*>(scales + (size_t)n0 * 32 + e);
        int c0 = e >> 5, g0 = e & 31;
        slds[g0 * 16 + c0]       = sv.x;
        slds[(g0 + 1) * 16 + c0] = sv.y;
    }

    const int kint0 = blockIdx.y * 512;      // int32 offset of block's k-range
    const int kbB   = blockIdx.y * 32;       // frag kb base
    const int grB   = blockIdx.y * 8;        // scale-group base
    const int dperm = (lane & 0x30) | ((lane & 3) << 2) | ((lane >> 2) & 3);

    #define PLOAD(u, sr)                                                       \
        _Pragma("unroll")                                                      \
        for (int ii = 0; ii < 4; ++ii) {                                       \
            sr[ii] = *reinterpret_cast<const i32x4*>(                          \
                packed + (size_t)(n0 + wave * 4 + ii) * (IN_F / 2)             \
                       + kint0 + (u) * 256 + lane * 4);                        \
        }

    #define PWRITE(u, sr)                                                      \
        _Pragma("unroll")                                                      \
        for (int ii = 0; ii < 4; ++ii) {                                       \
            int row = wave * 4 + ii;                                           \
            unsigned v = ((unsigned)(sr[ii][0] & 255))                         \
                       | ((unsigned)(sr[ii][1] & 255) << 8)                    \
                       | ((unsigned)(sr[ii][2] & 255) << 16)                   \
                       | ((unsigned)(sr[ii][3] & 255) << 24);                  \
            buf[(u) & 1][(row * 64 + dperm) ^ ((row & 7) << 2)] = v;           \
        }

    // prologue: both units' loads in flight; write unit 0
    i32x4 sB[4];
    {
        i32x4 sA[4];
        PLOAD(0, sA)
        PLOAD(1, sB)
        PWRITE(0, sA)
    }
    __syncthreads();

    f32x4 acc0 = (f32x4){0.f,0.f,0.f,0.f};   // batch 0-15
    f32x4 acc1 = (f32x4){0.f,0.f,0.f,0.f};   // batch 16-31

    const unsigned short* f0 = frag;
    const unsigned short* f1 = frag + 65536;

    #pragma unroll
    for (int u = 0; u < 2; ++u) {
        // A fragments for this unit (8 x 1KB contiguous, L2-resident)
        bf16x8 A0[4], A1[4];
        #pragma unroll
        for (int t = 0; t < 4; ++t) {
            int kb = kbB + u * 16 + wave * 4 + t;
            A0[t] = *reinterpret_cast<const bf16x8*>(f0 + ((size_t)kb * 64 + lane) * 8);
            A1[t] = *reinterpret_cast<const bf16x8*>(f1 + ((size_t)kb * 64 + lane) * 8);
        }

        i32x4 cdv = *reinterpret_cast<const i32x4*>(
            &buf[u & 1][(col * 64 + wave * 16 + g * 4) ^ ((col & 7) << 2)]);
        float sc = slds[(grB + u * 4 + wave) * 16 + col];

        f32x4 t0 = (f32x4){0.f,0.f,0.f,0.f};
        f32x4 t1 = (f32x4){0.f,0.f,0.f,0.f};
        #pragma unroll
        for (int t = 0; t < 4; ++t) {
            unsigned code = (unsigned)cdv[t];
            i32x4 bu;                            // bfrag once, both halves
            bu[0] = (int)tabu[code & 255u];
            bu[1] = (int)tabu[(code >> 8) & 255u];
            bu[2] = (int)tabu[(code >> 16) & 255u];
            bu[3] = (int)tabu[code >> 24];
            bf16x8 bf = __builtin_bit_cast(bf16x8, bu);
            t0 = __builtin_amdgcn_mfma_f32_16x16x32_bf16(A0[t], bf, t0, 0, 0, 0);
            t1 = __builtin_amdgcn_mfma_f32_16x16x32_bf16(A1[t], bf, t1, 0, 0, 0);
        }
        #pragma unroll
        for (int j = 0; j < 4; ++j) {
            acc0[j] = fmaf(sc, t0[j], acc0[j]);
            acc1[j] = fmaf(sc, t1[j], acc1[j]);
        }

        if (u == 0) { PWRITE(1, sB) }
        __syncthreads();   // u0: buf1 ready / u1: codes dead, red alias safe
    }

    // ---- cross-wave K-reduce in aliased LDS, atomic accumulate ----
    float* red = (float*)buf;
    #pragma unroll
    for (int j = 0; j < 4; ++j) {
        red[wave * 512 + j * 64 + lane]       = acc0[j];
        red[wave * 512 + (4 + j) * 64 + lane] = acc1[j];
    }
    __syncthreads();

    #pragma unroll
    for (int p = 0; p < 2; ++p) {
        int idx = p * 256 + tid;             // [0,512): b = idx>>4, c = idx&15
        int b   = idx >> 4;
        int c   = idx & 15;
        int h   = b >> 4;
        int r4  = b & 15;
        int j   = r4 & 3;
        int lg  = r4 >> 2;
        int slot = (h * 4 + j) * 64 + lg * 16 + c;
        float s = red[slot] + red[512 + slot] + red[1024 + slot] + red[1536 + slot];
        unsafeAtomicAdd(out + (size_t)b * OUT_F + n0 + c, s);
    }
}

// ---------------------------------------------------------------------------
extern "C" void kernel_launch(void* const* d_in, const int* in_sizes, int n_in,
                              void* d_out, int out_size, void* d_ws, size_t ws_size,
                              hipStream_t stream) {
    const float* x      = (const float*)d_in[0];
    const int*   packed = (const int*)d_in[1];
    const float* scales = (const float*)d_in[2];
    const float* bias   = (const float*)d_in[3];
    float* out = (float*)d_out;

    unsigned short* frag = (unsigned short*)d_ws;   // 256 KB

    prelude_kernel<<<408, 256, 0, stream>>>(x, bias, frag, out);
    nf4_gemm_kernel<<<dim3(GRID_N, KSPLIT), 256, 0, stream>>>(packed, scales, frag, out);
}